// Round 9
// baseline (2439.064 us; speedup 1.0000x reference)
//
#include <hip/hip_runtime.h>
#include <hip/hip_bf16.h>
#include <cstdint>
#include <cstddef>

#define BN 8192
#define MTOT 32768   // 4*BN

using bf16 = __hip_bfloat16;
typedef float f32x4 __attribute__((ext_vector_type(4)));
typedef short short8 __attribute__((ext_vector_type(8)));

__device__ __forceinline__ bf16 f2b(float v) { return __float2bfloat16(v); }
__device__ __forceinline__ float b2f(bf16 v) { return __bfloat162float(v); }
// sin(x)+cos(x) = sqrt(2)*sin(x+pi/4)
__device__ __forceinline__ float sincos_sum(float x) {
    return 1.41421356237f * __sinf(x + 0.78539816340f);
}

// Layouts are POSITION-MAJOR: k = pi*68 + ic, n = po*68 + oc.
template<int WS> struct WsCfg;
template<> struct WsCfg<5> { static constexpr int KD = 1728, NP = 1792, KTRUE = 1700; };
template<> struct WsCfg<4> { static constexpr int KD = 1088, NP = 1152, KTRUE = 1088; };
template<> struct WsCfg<3> { static constexpr int KD = 640,  NP = 640,  KTRUE = 612;  };

// ---------------- Z0 prep, LDS-staged: one block per batch element --------------
template<int WS, bool SRC_F32>
__global__ __launch_bounds__(256)
void zprep_block(const float* __restrict__ xF, const bf16* __restrict__ xB,
                 const float* __restrict__ cell, const float* __restrict__ isc,
                 bf16* __restrict__ Z, int m0g, int CM)
{
    constexpr int KD = WsCfg<WS>::KD;
    constexpr int KTRUE = 68 * WS * WS;
    const int b = blockIdx.x, tid = threadIdx.x;
    __shared__ float s[68][37];   // +1 pad: stride 37 (mod 32 = 5) -> conflict-free

    for (int i = tid; i < 64 * 36; i += 256) {
        int ic = i / 36, off = i % 36;
        size_t idx = ((size_t)b * 64 + ic) * 36 + off;
        float t = SRC_F32 ? xF[idx] : b2f(xB[idx]);
        s[ic][off] = sincos_sum(t);
    }
    if (tid < 2) {
        float t = sincos_sum(cell[b * 2 + tid]);
        #pragma unroll
        for (int off = 0; off < 36; off++) s[64 + tid][off] = t;
    }
    if (tid >= 64 && tid < 136) {
        int j = tid - 64;
        int ic = j / 36, off = j % 36;
        s[66 + ic][off] = sincos_sum(isc[((size_t)b * 2 + ic) * 36 + off]);
    }
    __syncthreads();

    for (int i = tid; i < 4 * KD; i += 256) {
        int q = i / KD, k = i % KD;
        int gm = q * BN + b;
        if (gm < m0g || gm >= m0g + CM) continue;
        float v = 0.f;
        if (k < KTRUE) {
            int pi = k / 68, ic = k % 68;
            int r = (q >> 1) * (6 - WS) + pi / WS;
            int c = (q & 1) * (6 - WS) + pi % WS;
            v = s[ic][r * 6 + c];
        }
        Z[(size_t)(gm - m0g) * KD + k] = f2b(v);
    }
}

// ---------------- dense conv-matrix builder (position-major) ---------------------
template<int WS>
__global__ void build_wdense(const float* __restrict__ w1, const float* __restrict__ w3,
                             bf16* __restrict__ W1d, bf16* __restrict__ W3d)
{
    constexpr int KD = WsCfg<WS>::KD, NP = WsCfg<WS>::NP;
    constexpr int KTRUE = 68 * WS * WS;
    constexpr unsigned per = (unsigned)NP * (unsigned)KD;
    unsigned e = blockIdx.x * 256u + threadIdx.x;
    if (e >= 2u * per) return;
    const float* src = (e < per) ? w1 : w3;
    bf16* dst = (e < per) ? W1d : W3d;
    unsigned i = (e < per) ? e : (e - per);
    int n = (int)(i / (unsigned)KD), k = (int)(i % (unsigned)KD);
    float v = 0.f;
    if (n < KTRUE && k < KTRUE) {
        int po = n / 68, oc = n % 68, ro = po / WS, co = po % WS;
        int pi = k / 68, ic = k % 68, ri = pi / WS, ci = pi % WS;
        int kr = ri - ro + 1, kc = ci - co + 1;
        if (kr >= 0 && kr < 3 && kc >= 0 && kc < 3)
            v = src[((oc * 68 + ic) * 3 + kr) * 3 + kc];
    }
    dst[i] = f2b(v);
}

// ---------------- linear weight repack: (640 x KD), k permuted to pos-major ------
template<int WS>
__global__ void repack_lin(const float* __restrict__ wl, bf16* __restrict__ WlP)
{
    constexpr int KD = WsCfg<WS>::KD;
    constexpr int KTRUE = 68 * WS * WS;
    unsigned e = blockIdx.x * 256u + threadIdx.x;
    if (e >= 640u * (unsigned)KD) return;
    int n = (int)(e / (unsigned)KD), k = (int)(e % (unsigned)KD);
    float v = 0.f;
    if (n < 576 && k < KTRUE) {
        int pi = k / 68, ic = k % 68;
        v = wl[(size_t)n * KTRUE + ic * (WS * WS) + pi];   // ref k-order = ic*ws^2+pi
    }
    WlP[e] = f2b(v);
}

__global__ void repack_fin(const float* __restrict__ fw, bf16* __restrict__ WfP)
{
    unsigned e = blockIdx.x * 256u + threadIdx.x;
    if (e >= 128u * 576u) return;
    unsigned n = e / 576u, k = e % 576u;
    WfP[e] = (n < 64u) ? f2b(fw[n * 576u + k]) : f2b(0.f);
}

// ---------------- all bias arrays (float), conv biases in pos-major n ------------
__global__ void build_bias(const float* __restrict__ b1, const float* __restrict__ b3,
                           const float* __restrict__ bl5, const float* __restrict__ bl4,
                           const float* __restrict__ bl3, const float* __restrict__ bfin,
                           float* __restrict__ bias)
{
    int e = blockIdx.x * 256 + threadIdx.x;
    if (e >= 9216) return;
    float v = 0.f;
    if (e < 1792)      { int n = e;        if (n < 1700) v = b1[n % 68]; }
    else if (e < 3584) { int n = e - 1792; if (n < 1700) v = b3[n % 68]; }
    else if (e < 4736) { int n = e - 3584; if (n < 1088) v = b1[n % 68]; }
    else if (e < 5888) { int n = e - 4736; if (n < 1088) v = b3[n % 68]; }
    else if (e < 6528) { int n = e - 5888; if (n < 612)  v = b1[n % 68]; }
    else if (e < 7168) { int n = e - 6528; if (n < 612)  v = b3[n % 68]; }
    else if (e < 7808) { int n = e - 7168; if (n < 576)  v = bl5[n]; }
    else if (e < 8448) { int n = e - 7808; if (n < 576)  v = bl4[n]; }
    else if (e < 9088) { int n = e - 8448; if (n < 576)  v = bl3[n]; }
    else               { int n = e - 9088; if (n < 64)   v = bfin[n]; }
    bias[e] = v;
}

// ---------------- final-GEMM A: corner(ws=3) gather of xbuf ----------------------
__global__ void afin_prep(const bf16* __restrict__ xb, bf16* __restrict__ Afin,
                          int m_start, int CM)
{
    unsigned e = blockIdx.x * 256u + threadIdx.x;
    if (e >= (unsigned)CM * 576u) return;
    int lm = (int)(e / 576u), k = (int)(e % 576u);
    int m = m_start + lm;
    int q = m >> 13, b = m & (BN - 1);
    int ch = k / 9, p = k % 9, pr = p / 3, pc = p % 3;
    int r = (q >> 1) * 3 + pr, c = (q & 1) * 3 + pc;
    Afin[e] = xb[((size_t)b * 64 + ch) * 36 + r * 6 + c];
}

__device__ __forceinline__ int imin(int a, int b) { return a < b ? a : b; }
__device__ __forceinline__ int imax(int a, int b) { return a > b ? a : b; }

// ---------------- MFMA GEMM: barrier-free, direct global->VGPR fragments ---------
// C[M,N] = A[M,K] @ B[N,K]^T. 1D grid = ntiles*mtiles, mtiles % 8 == 0.
// XCD swizzle: id&7 owns contiguous m-slabs, n fastest (A slab L2-resident).
// No LDS, no __syncthreads: each lane's MFMA fragment is 8 contiguous k-elems
// = one global_load_dwordx4; next-iter fragments double-buffered in registers.
// EPI: 0 bias+relu+sincos->C ; 1 bias+relu->C ; 2 bias+relu->xbuf scatter ;
//      3 bias,*xc->out(fp32)
template<int EPI, int WS>
__global__ __launch_bounds__(256)
void gemm_bt(const bf16* __restrict__ A, const bf16* __restrict__ Bm, int KD,
             const float* __restrict__ bias, int ntiles,
             bf16* __restrict__ C, int ldc, int nlimit,
             int m0g, bf16* __restrict__ xbuf_out,
             const bf16* __restrict__ xbuf_xc, float* __restrict__ outp)
{
    const int tid = threadIdx.x;
    const int wave = tid >> 6, lane = tid & 63;
    const int l15 = lane & 15, lq = lane >> 4;
    const int wr = (wave >> 1) * 64, wc = (wave & 1) * 64;

    const int id = blockIdx.x;
    const int mt8 = (int)gridDim.x / (ntiles * 8);   // m-tiles per XCD
    const int xcd = id & 7, local = id >> 3;
    const int m_idx = xcd * mt8 + local / ntiles;
    const int n_idx = local % ntiles;
    const int n0 = n_idx * 128, m0 = m_idx * 128;

    int klo = 0, khi = KD;
    if (WS > 0) {
        constexpr int ROWLEN = WS * 68;
        int po_lo = imin(n0 / 68, WS * WS - 1);
        int po_hi = imin((n0 + 127) / 68, WS * WS - 1);
        int r_lo = imax(po_lo / WS - 1, 0);
        int r_hi = imin(po_hi / WS + 1, WS - 1);
        klo = (r_lo * ROWLEN) & ~31;
        khi = imin(KD, ((r_hi + 1) * ROWLEN + 31) & ~31);
    }

    // bias prefetch (bias arrays are padded to cover the full n range)
    float bj[4];
    #pragma unroll
    for (int j = 0; j < 4; j++) bj[j] = bias[n0 + wc + j * 16 + l15];

    // per-fragment global pointers: lane reads 8 contiguous bf16 at k-offset
    const bf16* aP[4];
    const bf16* bP[4];
    #pragma unroll
    for (int i = 0; i < 4; i++)
        aP[i] = A + (size_t)(m0 + wr + i * 16 + l15) * KD + lq * 8;
    #pragma unroll
    for (int j = 0; j < 4; j++)
        bP[j] = Bm + (size_t)(n0 + wc + j * 16 + l15) * KD + lq * 8;

    f32x4 acc[4][4];
    #pragma unroll
    for (int i = 0; i < 4; i++)
        #pragma unroll
        for (int j = 0; j < 4; j++) { f32x4 z = {0.f, 0.f, 0.f, 0.f}; acc[i][j] = z; }

    short8 curA[4], curB[4], nxtA[4], nxtB[4];
    #pragma unroll
    for (int i = 0; i < 4; i++) curA[i] = *(const short8*)(aP[i] + klo);
    #pragma unroll
    for (int j = 0; j < 4; j++) curB[j] = *(const short8*)(bP[j] + klo);

    for (int k0 = klo; k0 < khi; k0 += 32) {
        int kn = (k0 + 32 < khi) ? (k0 + 32) : k0;   // keep prefetch in-bounds
        #pragma unroll
        for (int i = 0; i < 4; i++) nxtA[i] = *(const short8*)(aP[i] + kn);
        #pragma unroll
        for (int j = 0; j < 4; j++) nxtB[j] = *(const short8*)(bP[j] + kn);
        #pragma unroll
        for (int i = 0; i < 4; i++)
            #pragma unroll
            for (int j = 0; j < 4; j++)
                acc[i][j] = __builtin_amdgcn_mfma_f32_16x16x32_bf16(curA[i], curB[j], acc[i][j], 0, 0, 0);
        #pragma unroll
        for (int i = 0; i < 4; i++) curA[i] = nxtA[i];
        #pragma unroll
        for (int j = 0; j < 4; j++) curB[j] = nxtB[j];
    }

    #pragma unroll
    for (int i = 0; i < 4; i++) {
        #pragma unroll
        for (int j = 0; j < 4; j++) {
            int n = n0 + wc + j * 16 + l15;
            #pragma unroll
            for (int r = 0; r < 4; r++) {
                int m = m0 + wr + i * 16 + lq * 4 + r;
                float v = acc[i][j][r];
                if (EPI == 0) {
                    if (n < nlimit) {
                        v += bj[j]; v = fmaxf(v, 0.f); v = sincos_sum(v);
                        C[(size_t)m * ldc + n] = f2b(v);
                    }
                } else if (EPI == 1) {
                    if (n < nlimit) {
                        v += bj[j]; v = fmaxf(v, 0.f);
                        C[(size_t)m * ldc + n] = f2b(v);
                    }
                } else if (EPI == 2) {
                    if (n < 576) {
                        v += bj[j]; v = fmaxf(v, 0.f);
                        int gm = m0g + m;
                        int q = gm >> 13, b = gm & (BN - 1);
                        int ch = n / 9, p = n % 9, rr = p / 3, cc = p % 3;
                        int R = rr + (q >> 1) * 3, Cc = cc + (q & 1) * 3;
                        xbuf_out[((size_t)b * 64 + ch) * 36 + R * 6 + Cc] = f2b(v);
                    }
                } else {
                    if (n < 64) {
                        v += bj[j];
                        int gm = m0g + m;
                        int f = gm * 64 + n;
                        int b2 = f >> 8, rem = f & 255;
                        int ch2 = rem >> 2, ii = (rem >> 1) & 1, jj = rem & 1;
                        float xc = b2f(xbuf_xc[((size_t)b2 * 64 + ch2) * 36 + (2 + ii) * 6 + (2 + jj)]);
                        outp[f] = v * xc;
                    }
                }
            }
        }
    }
}

// ---------------- host-side per-ws pipeline --------------------------------------
template<int WS, bool SRC_F32>
static void run_ws(const float* xsrcF, const bf16* xsrcB, bf16* xdst,
                   const float* cell, const float* isc,
                   bf16* Za, bf16* Zb, const bf16* W1d, const bf16* W3d, const bf16* WlP,
                   const float* bias, int bo1, int bo3, int bol,
                   int nchunk, hipStream_t stream)
{
    constexpr int KD = WsCfg<WS>::KD, NP = WsCfg<WS>::NP;
    int CM = MTOT / nchunk;
    int mt = CM / 128;                       // divisible by 8 (256/nchunk, nchunk<=8)
    for (int c = 0; c < nchunk; c++) {
        int m0g = c * CM;
        zprep_block<WS, SRC_F32><<<BN, 256, 0, stream>>>(
            xsrcF, xsrcB, cell, isc, Za, m0g, CM);
        int nt12 = NP / 128;
        gemm_bt<0, WS><<<nt12 * mt, 256, 0, stream>>>(Za, W1d, KD, bias + bo1, nt12,
                                                      Zb, KD, KD, 0, nullptr, nullptr, nullptr);
        gemm_bt<1, WS><<<nt12 * mt, 256, 0, stream>>>(Zb, W3d, KD, bias + bo3, nt12,
                                                      Za, KD, KD, 0, nullptr, nullptr, nullptr);
        gemm_bt<2, 0><<<5 * mt, 256, 0, stream>>>(Za, WlP, KD, bias + bol, 5,
                                                  nullptr, 0, 0, m0g, xdst, nullptr, nullptr);
    }
}

extern "C" void kernel_launch(void* const* d_in, const int* in_sizes, int n_in,
                              void* d_out, int out_size, void* d_ws, size_t ws_size,
                              hipStream_t stream)
{
    const float* x    = (const float*)d_in[0];
    const float* cell = (const float*)d_in[1];
    const float* isc  = (const float*)d_in[2];
    const float* c1w  = (const float*)d_in[3];
    const float* c1b  = (const float*)d_in[4];
    const float* c3w  = (const float*)d_in[5];
    const float* c3b  = (const float*)d_in[6];
    const float* l5w  = (const float*)d_in[7];
    const float* l5b  = (const float*)d_in[8];
    const float* l4w  = (const float*)d_in[9];
    const float* l4b  = (const float*)d_in[10];
    const float* l3w  = (const float*)d_in[11];
    const float* l3b  = (const float*)d_in[12];
    const float* fw   = (const float*)d_in[13];
    const float* fb   = (const float*)d_in[14];

    char* base = (char*)d_ws;
    size_t cur = 0;
    auto take = [&](size_t bytes) -> char* {
        char* r = base + cur; cur += (bytes + 255) & ~(size_t)255; return r;
    };

    const size_t XB = (size_t)BN * 64 * 36 * 2;
    size_t wbytes = 2 * (1792ull * 1728 + 1152ull * 1088 + 640ull * 640) * 2
                  + (640ull * 1728 + 640ull * 1088 + 640ull * 640) * 2
                  + 128ull * 576 * 2 + 9216ull * 4 + 64 * 256;
    auto need = [&](int nc) -> size_t {
        size_t xb = (nc > 1) ? 2 * XB : XB;
        return xb + wbytes + 2 * ((size_t)(MTOT / nc) * 1728 * 2);
    };
    int nchunk = (ws_size >= need(1)) ? 1 : (ws_size >= need(2)) ? 2
               : (ws_size >= need(4)) ? 4 : 8;

    bf16* xbufA = (bf16*)take(XB);
    bf16* xbufB = (nchunk > 1) ? (bf16*)take(XB) : xbufA;
    bf16* w1d5 = (bf16*)take(1792ull * 1728 * 2);
    bf16* w3d5 = (bf16*)take(1792ull * 1728 * 2);
    bf16* w1d4 = (bf16*)take(1152ull * 1088 * 2);
    bf16* w3d4 = (bf16*)take(1152ull * 1088 * 2);
    bf16* w1d3 = (bf16*)take(640ull * 640 * 2);
    bf16* w3d3 = (bf16*)take(640ull * 640 * 2);
    bf16* wl5p = (bf16*)take(640ull * 1728 * 2);
    bf16* wl4p = (bf16*)take(640ull * 1088 * 2);
    bf16* wl3p = (bf16*)take(640ull * 640 * 2);
    bf16* wfp  = (bf16*)take(128ull * 576 * 2);
    float* biasb = (float*)take(9216ull * 4);
    int CM = MTOT / nchunk;
    bf16* Za = (bf16*)take((size_t)CM * 1728 * 2);
    bf16* Zb = (bf16*)take((size_t)CM * 1728 * 2);
    bf16* Afin = Za;

    auto nb = [](size_t t) { return dim3((unsigned)((t + 255) / 256)); };
    build_wdense<5><<<nb(2ull * 1792 * 1728), 256, 0, stream>>>(c1w, c3w, w1d5, w3d5);
    build_wdense<4><<<nb(2ull * 1152 * 1088), 256, 0, stream>>>(c1w, c3w, w1d4, w3d4);
    build_wdense<3><<<nb(2ull * 640 * 640), 256, 0, stream>>>(c1w, c3w, w1d3, w3d3);
    repack_lin<5><<<nb(640ull * 1728), 256, 0, stream>>>(l5w, wl5p);
    repack_lin<4><<<nb(640ull * 1088), 256, 0, stream>>>(l4w, wl4p);
    repack_lin<3><<<nb(640ull * 640), 256, 0, stream>>>(l3w, wl3p);
    repack_fin<<<nb(128ull * 576), 256, 0, stream>>>(fw, wfp);
    build_bias<<<36, 256, 0, stream>>>(c1b, c3b, l5b, l4b, l3b, fb, biasb);

    run_ws<5, true >(x, nullptr, xbufA, cell, isc, Za, Zb, w1d5, w3d5, wl5p, biasb,
                     0, 1792, 7168, nchunk, stream);
    run_ws<4, false>(nullptr, xbufA, xbufB, cell, isc, Za, Zb, w1d4, w3d4, wl4p, biasb,
                     3584, 4736, 7808, nchunk, stream);
    run_ws<3, false>(nullptr, xbufB, xbufA, cell, isc, Za, Zb, w1d3, w3d3, wl3p, biasb,
                     5888, 6528, 8448, nchunk, stream);

    for (int c = 0; c < nchunk; c++) {
        int m0g = c * CM;
        int mt = CM / 128;
        afin_prep<<<nb((size_t)CM * 576), 256, 0, stream>>>(xbufA, Afin, m0g, CM);
        gemm_bt<3, 0><<<mt, 256, 0, stream>>>(Afin, wfp, 576, biasb + 9088, 1,
                                              nullptr, 0, 0, m0g, nullptr,
                                              xbufA, (float*)d_out);
    }
}

// Round 10
// 1339.913 us; speedup vs baseline: 1.8203x; 1.8203x over previous
//
#include <hip/hip_runtime.h>
#include <hip/hip_bf16.h>
#include <cstdint>
#include <cstddef>

#define BN 8192
#define MTOT 32768   // 4*BN

using bf16 = __hip_bfloat16;
typedef float f32x4 __attribute__((ext_vector_type(4)));
typedef short short8 __attribute__((ext_vector_type(8)));

__device__ __forceinline__ bf16 f2b(float v) { return __float2bfloat16(v); }
__device__ __forceinline__ float b2f(bf16 v) { return __bfloat162float(v); }
// sin(x)+cos(x) = sqrt(2)*sin(x+pi/4)
__device__ __forceinline__ float sincos_sum(float x) {
    return 1.41421356237f * __sinf(x + 0.78539816340f);
}

// Layouts are POSITION-MAJOR: k = pi*68 + ic, n = po*68 + oc.
template<int WS> struct WsCfg;
template<> struct WsCfg<5> { static constexpr int KD = 1728, NP = 1792, KTRUE = 1700; };
template<> struct WsCfg<4> { static constexpr int KD = 1088, NP = 1152, KTRUE = 1088; };
template<> struct WsCfg<3> { static constexpr int KD = 640,  NP = 640,  KTRUE = 612;  };

// ---------------- Z0 prep, LDS-staged: one block per batch element --------------
template<int WS, bool SRC_F32>
__global__ __launch_bounds__(256)
void zprep_block(const float* __restrict__ xF, const bf16* __restrict__ xB,
                 const float* __restrict__ cell, const float* __restrict__ isc,
                 bf16* __restrict__ Z, int m0g, int CM)
{
    constexpr int KD = WsCfg<WS>::KD;
    constexpr int KTRUE = 68 * WS * WS;
    const int b = blockIdx.x, tid = threadIdx.x;
    __shared__ float s[68][37];   // +1 pad: stride 37 (mod 32 = 5) -> conflict-free

    for (int i = tid; i < 64 * 36; i += 256) {
        int ic = i / 36, off = i % 36;
        size_t idx = ((size_t)b * 64 + ic) * 36 + off;
        float t = SRC_F32 ? xF[idx] : b2f(xB[idx]);
        s[ic][off] = sincos_sum(t);
    }
    if (tid < 2) {
        float t = sincos_sum(cell[b * 2 + tid]);
        #pragma unroll
        for (int off = 0; off < 36; off++) s[64 + tid][off] = t;
    }
    if (tid >= 64 && tid < 136) {
        int j = tid - 64;
        int ic = j / 36, off = j % 36;
        s[66 + ic][off] = sincos_sum(isc[((size_t)b * 2 + ic) * 36 + off]);
    }
    __syncthreads();

    for (int i = tid; i < 4 * KD; i += 256) {
        int q = i / KD, k = i % KD;
        int gm = q * BN + b;
        if (gm < m0g || gm >= m0g + CM) continue;
        float v = 0.f;
        if (k < KTRUE) {
            int pi = k / 68, ic = k % 68;
            int r = (q >> 1) * (6 - WS) + pi / WS;
            int c = (q & 1) * (6 - WS) + pi % WS;
            v = s[ic][r * 6 + c];
        }
        Z[(size_t)(gm - m0g) * KD + k] = f2b(v);
    }
}

// ---------------- dense conv-matrix builder (position-major) ---------------------
template<int WS>
__global__ void build_wdense(const float* __restrict__ w1, const float* __restrict__ w3,
                             bf16* __restrict__ W1d, bf16* __restrict__ W3d)
{
    constexpr int KD = WsCfg<WS>::KD, NP = WsCfg<WS>::NP;
    constexpr int KTRUE = 68 * WS * WS;
    constexpr unsigned per = (unsigned)NP * (unsigned)KD;
    unsigned e = blockIdx.x * 256u + threadIdx.x;
    if (e >= 2u * per) return;
    const float* src = (e < per) ? w1 : w3;
    bf16* dst = (e < per) ? W1d : W3d;
    unsigned i = (e < per) ? e : (e - per);
    int n = (int)(i / (unsigned)KD), k = (int)(i % (unsigned)KD);
    float v = 0.f;
    if (n < KTRUE && k < KTRUE) {
        int po = n / 68, oc = n % 68, ro = po / WS, co = po % WS;
        int pi = k / 68, ic = k % 68, ri = pi / WS, ci = pi % WS;
        int kr = ri - ro + 1, kc = ci - co + 1;
        if (kr >= 0 && kr < 3 && kc >= 0 && kc < 3)
            v = src[((oc * 68 + ic) * 3 + kr) * 3 + kc];
    }
    dst[i] = f2b(v);
}

// ---------------- linear weight repack: (640 x KD), k permuted to pos-major ------
template<int WS>
__global__ void repack_lin(const float* __restrict__ wl, bf16* __restrict__ WlP)
{
    constexpr int KD = WsCfg<WS>::KD;
    constexpr int KTRUE = 68 * WS * WS;
    unsigned e = blockIdx.x * 256u + threadIdx.x;
    if (e >= 640u * (unsigned)KD) return;
    int n = (int)(e / (unsigned)KD), k = (int)(e % (unsigned)KD);
    float v = 0.f;
    if (n < 576 && k < KTRUE) {
        int pi = k / 68, ic = k % 68;
        v = wl[(size_t)n * KTRUE + ic * (WS * WS) + pi];   // ref k-order = ic*ws^2+pi
    }
    WlP[e] = f2b(v);
}

__global__ void repack_fin(const float* __restrict__ fw, bf16* __restrict__ WfP)
{
    unsigned e = blockIdx.x * 256u + threadIdx.x;
    if (e >= 128u * 576u) return;
    unsigned n = e / 576u, k = e % 576u;
    WfP[e] = (n < 64u) ? f2b(fw[n * 576u + k]) : f2b(0.f);
}

// ---------------- all bias arrays (float), conv biases in pos-major n ------------
__global__ void build_bias(const float* __restrict__ b1, const float* __restrict__ b3,
                           const float* __restrict__ bl5, const float* __restrict__ bl4,
                           const float* __restrict__ bl3, const float* __restrict__ bfin,
                           float* __restrict__ bias)
{
    int e = blockIdx.x * 256 + threadIdx.x;
    if (e >= 9216) return;
    float v = 0.f;
    if (e < 1792)      { int n = e;        if (n < 1700) v = b1[n % 68]; }
    else if (e < 3584) { int n = e - 1792; if (n < 1700) v = b3[n % 68]; }
    else if (e < 4736) { int n = e - 3584; if (n < 1088) v = b1[n % 68]; }
    else if (e < 5888) { int n = e - 4736; if (n < 1088) v = b3[n % 68]; }
    else if (e < 6528) { int n = e - 5888; if (n < 612)  v = b1[n % 68]; }
    else if (e < 7168) { int n = e - 6528; if (n < 612)  v = b3[n % 68]; }
    else if (e < 7808) { int n = e - 7168; if (n < 576)  v = bl5[n]; }
    else if (e < 8448) { int n = e - 7808; if (n < 576)  v = bl4[n]; }
    else if (e < 9088) { int n = e - 8448; if (n < 576)  v = bl3[n]; }
    else               { int n = e - 9088; if (n < 64)   v = bfin[n]; }
    bias[e] = v;
}

// ---------------- async global->LDS, 16B per lane (m97 idiom) --------------------
__device__ __forceinline__ void gload_lds16(const bf16* g, const bf16* lds_wave_base)
{
    unsigned off = (unsigned)(uintptr_t)lds_wave_base;
    off = __builtin_amdgcn_readfirstlane(off);
    __builtin_amdgcn_global_load_lds((const __attribute__((address_space(1))) unsigned int*)g,
                                     (__attribute__((address_space(3))) unsigned int*)off,
                                     16, 0, 0);
}

__device__ __forceinline__ int imin(int a, int b) { return a < b ? a : b; }
__device__ __forceinline__ int imax(int a, int b) { return a > b ? a : b; }

// ---------------- MFMA GEMM: rect K-banding + XCD swizzle (r7 structure) ---------
// C[M,N] = A[M,K] @ B[N,K]^T. 1D grid = ntiles*mtiles, mtiles % 8 == 0.
// XCD swizzle: id&7 owns contiguous m-slabs, n fastest (A slab L2-resident).
// WS>0: conv matrix is block-banded in position-major order. If the tile's output
// positions share one row ro, k is restricted per tap-row ri to cols
// [co_lo-1, co_hi+1] (disjoint 32-aligned sub-spans: col gap >= 68 > 62).
// EPI: 0 bias+relu+sincos->C ; 1 bias+relu->C ; 2 bias+relu->xbuf scatter ;
//      3 bias,*xc(from Afin)->out(fp32)
template<int EPI, int WS>
__global__ __launch_bounds__(256)
void gemm_bt(const bf16* __restrict__ A, const bf16* __restrict__ Bm, int KD,
             const float* __restrict__ bias, int ntiles,
             bf16* __restrict__ C, int ldc, int nlimit,
             int m0g, bf16* __restrict__ xbuf_out,
             const bf16* __restrict__ afin_xc, float* __restrict__ outp)
{
    __shared__ bf16 As[128 * 32];
    __shared__ bf16 Bs[128 * 32];
    const int tid = threadIdx.x;
    const int wave = tid >> 6, lane = tid & 63;
    const int l15 = lane & 15, lq = lane >> 4;
    const int wr = (wave >> 1) * 64, wc = (wave & 1) * 64;

    const int id = blockIdx.x;
    const int mt8 = (int)gridDim.x / (ntiles * 8);   // m-tiles per XCD
    const int xcd = id & 7, local = id >> 3;
    const int m_idx = xcd * mt8 + local / ntiles;
    const int n_idx = local % ntiles;
    const int n0 = n_idx * 128, m0 = m_idx * 128;

    int nspans = 1, sbeg[4], send[4];
    sbeg[0] = 0; send[0] = KD;
    if (WS > 0) {
        int po_lo = imin(n0 / 68, WS * WS - 1);
        int po_hi = imin((n0 + 127) / 68, WS * WS - 1);
        int ro_lo = po_lo / WS, ro_hi = po_hi / WS;
        int r_lo = imax(ro_lo - 1, 0), r_hi = imin(ro_hi + 1, WS - 1);
        int ci_lo = 0, ci_hi = WS - 1;
        if (ro_lo == ro_hi) {
            ci_lo = imax(po_lo % WS - 1, 0);
            ci_hi = imin(po_hi % WS + 1, WS - 1);
        }
        if (ci_lo == 0 && ci_hi == WS - 1) {
            sbeg[0] = (r_lo * WS * 68) & ~31;
            send[0] = imin(KD, ((r_hi + 1) * WS * 68 + 31) & ~31);
        } else {
            nspans = 0;
            for (int ri = r_lo; ri <= r_hi; ri++) {
                sbeg[nspans] = ((ri * WS + ci_lo) * 68) & ~31;
                send[nspans] = imin(KD, (((ri * WS + ci_hi + 1) * 68) + 31) & ~31);
                nspans++;
            }
        }
    }

    // bias prefetch (bias arrays are padded to cover the full padded n range)
    float bj[4];
    #pragma unroll
    for (int j = 0; j < 4; j++) bj[j] = bias[n0 + wc + j * 16 + l15];

    const bf16* Ab = A + (size_t)m0 * KD;
    const bf16* Bb = Bm + (size_t)n0 * KD;
    const int srow = tid >> 2, scol = (tid & 3) * 8;
    const bf16* aG0 = Ab + (size_t)srow * KD + scol;
    const bf16* aG1 = Ab + (size_t)(srow + 64) * KD + scol;
    const bf16* bG0 = Bb + (size_t)srow * KD + scol;
    const bf16* bG1 = Bb + (size_t)(srow + 64) * KD + scol;
    const bf16* lA0 = &As[wave * 512];
    const bf16* lA1 = &As[2048 + wave * 512];
    const bf16* lB0 = &Bs[wave * 512];
    const bf16* lB1 = &Bs[2048 + wave * 512];

    f32x4 acc[4][4];
    #pragma unroll
    for (int i = 0; i < 4; i++)
        #pragma unroll
        for (int j = 0; j < 4; j++) { f32x4 z = {0.f, 0.f, 0.f, 0.f}; acc[i][j] = z; }

    for (int s = 0; s < nspans; s++) {
        for (int k0 = sbeg[s]; k0 < send[s]; k0 += 32) {
            gload_lds16(aG0 + k0, lA0);
            gload_lds16(aG1 + k0, lA1);
            gload_lds16(bG0 + k0, lB0);
            gload_lds16(bG1 + k0, lB1);
            __syncthreads();
            short8 af[4], bg[4];
            #pragma unroll
            for (int i = 0; i < 4; i++) af[i] = *(const short8*)&As[(wr + i * 16 + l15) * 32 + lq * 8];
            #pragma unroll
            for (int j = 0; j < 4; j++) bg[j] = *(const short8*)&Bs[(wc + j * 16 + l15) * 32 + lq * 8];
            #pragma unroll
            for (int i = 0; i < 4; i++)
                #pragma unroll
                for (int j = 0; j < 4; j++)
                    acc[i][j] = __builtin_amdgcn_mfma_f32_16x16x32_bf16(af[i], bg[j], acc[i][j], 0, 0, 0);
            __syncthreads();
        }
    }

    #pragma unroll
    for (int i = 0; i < 4; i++) {
        #pragma unroll
        for (int j = 0; j < 4; j++) {
            int n = n0 + wc + j * 16 + l15;
            #pragma unroll
            for (int r = 0; r < 4; r++) {
                int m = m0 + wr + i * 16 + lq * 4 + r;
                float v = acc[i][j][r];
                if (EPI == 0) {
                    if (n < nlimit) {
                        v += bj[j]; v = fmaxf(v, 0.f); v = sincos_sum(v);
                        C[(size_t)m * ldc + n] = f2b(v);
                    }
                } else if (EPI == 1) {
                    if (n < nlimit) {
                        v += bj[j]; v = fmaxf(v, 0.f);
                        C[(size_t)m * ldc + n] = f2b(v);
                    }
                } else if (EPI == 2) {
                    if (n < 576) {
                        v += bj[j]; v = fmaxf(v, 0.f);
                        int gm = m0g + m;
                        int q = gm >> 13, b = gm & (BN - 1);
                        int ch = n / 9, p = n % 9, rr = p / 3, cc = p % 3;
                        int R = rr + (q >> 1) * 3, Cc = cc + (q & 1) * 3;
                        xbuf_out[((size_t)b * 64 + ch) * 36 + R * 6 + Cc] = f2b(v);
                    }
                } else {
                    if (n < 64) {
                        v += bj[j];
                        int gm = m0g + m;
                        int f = gm * 64 + n;        // c-flat == out-flat (reshape keeps order)
                        int b2 = f >> 8, rem = f & 255;
                        int ch2 = rem >> 2, ii = (rem >> 1) & 1, jj = rem & 1;
                        // xc[b2][ch2][ii][jj] = x[..][2+ii][2+jj] -> Afin slot:
                        int qq = ii * 2 + jj;
                        const int offt[4] = {8, 6, 2, 0};
                        float xc = b2f(afin_xc[((size_t)qq * BN + b2) * 576 + ch2 * 9 + offt[qq]]);
                        outp[f] = v * xc;
                    }
                }
            }
        }
    }
}

// ---------------- host-side per-ws pipeline --------------------------------------
// afin != nullptr (ws=3): lin-GEMM writes Afin directly (identity layout, EPI1).
template<int WS, bool SRC_F32>
static void run_ws(const float* xsrcF, const bf16* xsrcB, bf16* xdst, bf16* afin,
                   const float* cell, const float* isc,
                   bf16* Za, bf16* Zb, const bf16* W1d, const bf16* W3d, const bf16* WlP,
                   const float* bias, int bo1, int bo3, int bol,
                   int nchunk, hipStream_t stream)
{
    constexpr int KD = WsCfg<WS>::KD, NP = WsCfg<WS>::NP;
    int CM = MTOT / nchunk;
    int mt = CM / 128;                       // divisible by 8 (256/nchunk, nchunk<=8)
    for (int c = 0; c < nchunk; c++) {
        int m0g = c * CM;
        zprep_block<WS, SRC_F32><<<BN, 256, 0, stream>>>(
            xsrcF, xsrcB, cell, isc, Za, m0g, CM);
        int nt12 = NP / 128;
        gemm_bt<0, WS><<<nt12 * mt, 256, 0, stream>>>(Za, W1d, KD, bias + bo1, nt12,
                                                      Zb, KD, KD, 0, nullptr, nullptr, nullptr);
        gemm_bt<1, WS><<<nt12 * mt, 256, 0, stream>>>(Zb, W3d, KD, bias + bo3, nt12,
                                                      Za, KD, KD, 0, nullptr, nullptr, nullptr);
        if (afin) {
            gemm_bt<1, 0><<<5 * mt, 256, 0, stream>>>(Za, WlP, KD, bias + bol, 5,
                                                      afin + (size_t)m0g * 576, 576, 576,
                                                      0, nullptr, nullptr, nullptr);
        } else {
            gemm_bt<2, 0><<<5 * mt, 256, 0, stream>>>(Za, WlP, KD, bias + bol, 5,
                                                      nullptr, 0, 0, m0g, xdst, nullptr, nullptr);
        }
    }
}

extern "C" void kernel_launch(void* const* d_in, const int* in_sizes, int n_in,
                              void* d_out, int out_size, void* d_ws, size_t ws_size,
                              hipStream_t stream)
{
    const float* x    = (const float*)d_in[0];
    const float* cell = (const float*)d_in[1];
    const float* isc  = (const float*)d_in[2];
    const float* c1w  = (const float*)d_in[3];
    const float* c1b  = (const float*)d_in[4];
    const float* c3w  = (const float*)d_in[5];
    const float* c3b  = (const float*)d_in[6];
    const float* l5w  = (const float*)d_in[7];
    const float* l5b  = (const float*)d_in[8];
    const float* l4w  = (const float*)d_in[9];
    const float* l4b  = (const float*)d_in[10];
    const float* l3w  = (const float*)d_in[11];
    const float* l3b  = (const float*)d_in[12];
    const float* fw   = (const float*)d_in[13];
    const float* fb   = (const float*)d_in[14];

    char* base = (char*)d_ws;
    size_t cur = 0;
    auto take = [&](size_t bytes) -> char* {
        char* r = base + cur; cur += (bytes + 255) & ~(size_t)255; return r;
    };

    const size_t XB = (size_t)BN * 64 * 36 * 2;
    const size_t AFB = (size_t)MTOT * 576 * 2;
    size_t wbytes = 2 * (1792ull * 1728 + 1152ull * 1088 + 640ull * 640) * 2
                  + (640ull * 1728 + 640ull * 1088 + 640ull * 640) * 2
                  + 128ull * 576 * 2 + 9216ull * 4 + 64 * 256;
    auto need = [&](int nc) -> size_t {
        size_t xb = (nc > 1) ? 2 * XB : XB;
        return xb + AFB + wbytes + 2 * ((size_t)(MTOT / nc) * 1728 * 2);
    };
    int nchunk = (ws_size >= need(1)) ? 1 : (ws_size >= need(2)) ? 2
               : (ws_size >= need(4)) ? 4 : 8;

    bf16* xbufA = (bf16*)take(XB);
    bf16* xbufB = (nchunk > 1) ? (bf16*)take(XB) : xbufA;
    bf16* afinb = (bf16*)take(AFB);
    bf16* w1d5 = (bf16*)take(1792ull * 1728 * 2);
    bf16* w3d5 = (bf16*)take(1792ull * 1728 * 2);
    bf16* w1d4 = (bf16*)take(1152ull * 1088 * 2);
    bf16* w3d4 = (bf16*)take(1152ull * 1088 * 2);
    bf16* w1d3 = (bf16*)take(640ull * 640 * 2);
    bf16* w3d3 = (bf16*)take(640ull * 640 * 2);
    bf16* wl5p = (bf16*)take(640ull * 1728 * 2);
    bf16* wl4p = (bf16*)take(640ull * 1088 * 2);
    bf16* wl3p = (bf16*)take(640ull * 640 * 2);
    bf16* wfp  = (bf16*)take(128ull * 576 * 2);
    float* biasb = (float*)take(9216ull * 4);
    int CM = MTOT / nchunk;
    bf16* Za = (bf16*)take((size_t)CM * 1728 * 2);
    bf16* Zb = (bf16*)take((size_t)CM * 1728 * 2);

    auto nb = [](size_t t) { return dim3((unsigned)((t + 255) / 256)); };
    build_wdense<5><<<nb(2ull * 1792 * 1728), 256, 0, stream>>>(c1w, c3w, w1d5, w3d5);
    build_wdense<4><<<nb(2ull * 1152 * 1088), 256, 0, stream>>>(c1w, c3w, w1d4, w3d4);
    build_wdense<3><<<nb(2ull * 640 * 640), 256, 0, stream>>>(c1w, c3w, w1d3, w3d3);
    repack_lin<5><<<nb(640ull * 1728), 256, 0, stream>>>(l5w, wl5p);
    repack_lin<4><<<nb(640ull * 1088), 256, 0, stream>>>(l4w, wl4p);
    repack_lin<3><<<nb(640ull * 640), 256, 0, stream>>>(l3w, wl3p);
    repack_fin<<<nb(128ull * 576), 256, 0, stream>>>(fw, wfp);
    build_bias<<<36, 256, 0, stream>>>(c1b, c3b, l5b, l4b, l3b, fb, biasb);

    run_ws<5, true >(x, nullptr, xbufA, nullptr, cell, isc, Za, Zb, w1d5, w3d5, wl5p,
                     biasb, 0, 1792, 7168, nchunk, stream);
    run_ws<4, false>(nullptr, xbufA, xbufB, nullptr, cell, isc, Za, Zb, w1d4, w3d4, wl4p,
                     biasb, 3584, 4736, 7808, nchunk, stream);
    run_ws<3, false>(nullptr, xbufB, nullptr, afinb, cell, isc, Za, Zb, w1d3, w3d3, wl3p,
                     biasb, 5888, 6528, 8448, nchunk, stream);

    for (int c = 0; c < nchunk; c++) {
        int m0g = c * CM;
        int mt = CM / 128;
        gemm_bt<3, 0><<<mt, 256, 0, stream>>>(afinb + (size_t)m0g * 576, wfp, 576,
                                              biasb + 9088, 1, nullptr, 0, 0, m0g,
                                              nullptr, afinb, (float*)d_out);
    }
}

// Round 11
// 1339.680 us; speedup vs baseline: 1.8206x; 1.0002x over previous
//
#include <hip/hip_runtime.h>
#include <hip/hip_bf16.h>
#include <cstdint>
#include <cstddef>

#define BN 8192
#define MTOT 32768   // 4*BN

using bf16 = __hip_bfloat16;
typedef float f32x4 __attribute__((ext_vector_type(4)));
typedef short short8 __attribute__((ext_vector_type(8)));

__device__ __forceinline__ bf16 f2b(float v) { return __float2bfloat16(v); }
__device__ __forceinline__ float b2f(bf16 v) { return __bfloat162float(v); }
// sin(x)+cos(x) = sqrt(2)*sin(x+pi/4)
__device__ __forceinline__ float sincos_sum(float x) {
    return 1.41421356237f * __sinf(x + 0.78539816340f);
}

// Layouts are POSITION-MAJOR: k = pi*68 + ic, n = po*68 + oc.
template<int WS> struct WsCfg;
template<> struct WsCfg<5> { static constexpr int KD = 1728, NP = 1792, KTRUE = 1700; };
template<> struct WsCfg<4> { static constexpr int KD = 1088, NP = 1152, KTRUE = 1088; };
template<> struct WsCfg<3> { static constexpr int KD = 640,  NP = 640,  KTRUE = 612;  };

// ---------------- Z0 prep (ws=5 only now), LDS-staged, one block per b ----------
__global__ __launch_bounds__(256)
void zprep_block(const float* __restrict__ xF, const float* __restrict__ cell,
                 const float* __restrict__ isc, bf16* __restrict__ Z,
                 int m0g, int CM)
{
    constexpr int KD = 1728, KTRUE = 1700;
    const int b = blockIdx.x, tid = threadIdx.x;
    __shared__ float s[68][37];   // stride 37 words (mod 32 = 5) -> conflict-free

    for (int i = tid; i < 64 * 36; i += 256) {
        int ic = i / 36, off = i % 36;
        s[ic][off] = sincos_sum(xF[((size_t)b * 64 + ic) * 36 + off]);
    }
    if (tid < 2) {
        float t = sincos_sum(cell[b * 2 + tid]);
        #pragma unroll
        for (int off = 0; off < 36; off++) s[64 + tid][off] = t;
    }
    if (tid >= 64 && tid < 136) {
        int j = tid - 64;
        int ic = j / 36, off = j % 36;
        s[66 + ic][off] = sincos_sum(isc[((size_t)b * 2 + ic) * 36 + off]);
    }
    __syncthreads();

    for (int i = tid; i < 4 * KD; i += 256) {
        int q = i / KD, k = i % KD;
        int gm = q * BN + b;
        if (gm < m0g || gm >= m0g + CM) continue;
        float v = 0.f;
        if (k < KTRUE) {
            int pi = k / 68, ic = k % 68;
            int r = (q >> 1) + pi / 5;       // (6-WS)=1
            int c = (q & 1) + pi % 5;
            v = s[ic][r * 6 + c];
        }
        Z[(size_t)(gm - m0g) * KD + k] = f2b(v);
    }
}

// ---------------- megabuild: all weights/bias/const-cols in ONE kernel -----------
template<int WSv>
__device__ __forceinline__ bf16 conv_elem(const float* __restrict__ src, int n, int k)
{
    constexpr int KTRUE = 68 * WSv * WSv;
    float v = 0.f;
    if (n < KTRUE && k < KTRUE) {
        int po = n / 68, oc = n % 68, ro = po / WSv, co = po % WSv;
        int pi = k / 68, ic = k % 68, ri = pi / WSv, ci = pi % WSv;
        int kr = ri - ro + 1, kc = ci - co + 1;
        if (kr >= 0 && kr < 3 && kc >= 0 && kc < 3)
            v = src[((oc * 68 + ic) * 3 + kr) * 3 + kc];
    }
    return f2b(v);
}
template<int WSv>
__device__ __forceinline__ bf16 lin_elem(const float* __restrict__ wl, int n, int k)
{
    constexpr int KTRUE = 68 * WSv * WSv;
    float v = 0.f;
    if (n < 576 && k < KTRUE) {
        int pi = k / 68, ic = k % 68;
        v = wl[(size_t)n * KTRUE + ic * (WSv * WSv) + pi];  // ref k-order = ic*ws^2+pi
    }
    return f2b(v);
}

__global__ void megabuild(const float* __restrict__ c1w, const float* __restrict__ c3w,
                          const float* __restrict__ l5w, const float* __restrict__ l4w,
                          const float* __restrict__ l3w, const float* __restrict__ fw,
                          const float* __restrict__ c1b, const float* __restrict__ c3b,
                          const float* __restrict__ bl5, const float* __restrict__ bl4,
                          const float* __restrict__ bl3, const float* __restrict__ bfin,
                          const float* __restrict__ cell, const float* __restrict__ isc,
                          bf16* __restrict__ w1d5, bf16* __restrict__ w3d5,
                          bf16* __restrict__ w1d4, bf16* __restrict__ w3d4,
                          bf16* __restrict__ w1d3, bf16* __restrict__ w3d3,
                          bf16* __restrict__ wl5p, bf16* __restrict__ wl4p,
                          bf16* __restrict__ wl3p, bf16* __restrict__ wfp,
                          float* __restrict__ bias,
                          bf16* __restrict__ Z4, bf16* __restrict__ Z3)
{
    constexpr unsigned S0 = 2u*1792*1728, S1 = 2u*1152*1088, S2 = 2u*640*640;
    constexpr unsigned S3 = 640u*1728, S4 = 640u*1088, S5 = 640u*640;
    constexpr unsigned S6 = 128u*576, S7 = 9216;
    constexpr unsigned S8 = 4u*8192*16*4, S9 = 4u*8192*9*4, S10 = 32768u*28;
    constexpr unsigned O1=S0, O2=O1+S1, O3=O2+S2, O4=O3+S3, O5=O4+S4, O6=O5+S5,
                       O7=O6+S6, O8=O7+S7, O9=O8+S8, O10=O9+S9, OT=O10+S10;
    unsigned e = blockIdx.x * 256u + threadIdx.x;
    if (e >= OT) return;
    if (e < O1) {
        constexpr unsigned per = 1792u*1728;
        unsigned i = (e < per) ? e : e - per;
        bf16* dst = (e < per) ? w1d5 : w3d5;
        const float* src = (e < per) ? c1w : c3w;
        dst[i] = conv_elem<5>(src, (int)(i / 1728u), (int)(i % 1728u));
    } else if (e < O2) {
        unsigned i0 = e - O1; constexpr unsigned per = 1152u*1088;
        unsigned i = (i0 < per) ? i0 : i0 - per;
        bf16* dst = (i0 < per) ? w1d4 : w3d4;
        const float* src = (i0 < per) ? c1w : c3w;
        dst[i] = conv_elem<4>(src, (int)(i / 1088u), (int)(i % 1088u));
    } else if (e < O3) {
        unsigned i0 = e - O2; constexpr unsigned per = 640u*640;
        unsigned i = (i0 < per) ? i0 : i0 - per;
        bf16* dst = (i0 < per) ? w1d3 : w3d3;
        const float* src = (i0 < per) ? c1w : c3w;
        dst[i] = conv_elem<3>(src, (int)(i / 640u), (int)(i % 640u));
    } else if (e < O4) {
        unsigned i = e - O3;
        wl5p[i] = lin_elem<5>(l5w, (int)(i / 1728u), (int)(i % 1728u));
    } else if (e < O5) {
        unsigned i = e - O4;
        wl4p[i] = lin_elem<4>(l4w, (int)(i / 1088u), (int)(i % 1088u));
    } else if (e < O6) {
        unsigned i = e - O5;
        wl3p[i] = lin_elem<3>(l3w, (int)(i / 640u), (int)(i % 640u));
    } else if (e < O7) {
        unsigned i = e - O6, n = i / 576u, k = i % 576u;
        wfp[i] = (n < 64u) ? f2b(fw[n * 576u + k]) : f2b(0.f);
    } else if (e < O8) {
        int i = (int)(e - O7);
        float v = 0.f;
        if (i < 1792)      { int n = i;        if (n < 1700) v = c1b[n % 68]; }
        else if (i < 3584) { int n = i - 1792; if (n < 1700) v = c3b[n % 68]; }
        else if (i < 4736) { int n = i - 3584; if (n < 1088) v = c1b[n % 68]; }
        else if (i < 5888) { int n = i - 4736; if (n < 1088) v = c3b[n % 68]; }
        else if (i < 6528) { int n = i - 5888; if (n < 612)  v = c1b[n % 68]; }
        else if (i < 7168) { int n = i - 6528; if (n < 612)  v = c3b[n % 68]; }
        else if (i < 7808) { int n = i - 7168; if (n < 576)  v = bl5[n]; }
        else if (i < 8448) { int n = i - 7808; if (n < 576)  v = bl4[n]; }
        else if (i < 9088) { int n = i - 8448; if (n < 576)  v = bl3[n]; }
        else               { int n = i - 9088; if (n < 64)   v = bfin[n]; }
        bias[i] = v;
    } else if (e < O9) {
        // Z4 const cols (cell/isc), ic = 64..67
        unsigned i = e - O8;
        int j = (int)(i & 3u); i >>= 2;
        int pi = (int)(i & 15u); i >>= 4;
        int b = (int)(i & 8191u); int q = (int)(i >> 13);
        float t;
        if (j < 2) t = cell[b * 2 + j];
        else {
            int r = (q >> 1) * 2 + pi / 4, c = (q & 1) * 2 + pi % 4;
            t = isc[((size_t)b * 2 + (j - 2)) * 36 + r * 6 + c];
        }
        Z4[((size_t)q * BN + b) * 1088 + pi * 68 + 64 + j] = f2b(sincos_sum(t));
    } else if (e < O10) {
        // Z3 const cols
        unsigned i = e - O9;
        int j = (int)(i & 3u); i >>= 2;
        int pi = (int)(i % 9u); i /= 9u;
        int b = (int)(i & 8191u); int q = (int)(i >> 13);
        float t;
        if (j < 2) t = cell[b * 2 + j];
        else {
            int r = (q >> 1) * 3 + pi / 3, c = (q & 1) * 3 + pi % 3;
            t = isc[((size_t)b * 2 + (j - 2)) * 36 + r * 6 + c];
        }
        Z3[((size_t)q * BN + b) * 640 + pi * 68 + 64 + j] = f2b(sincos_sum(t));
    } else {
        // Z3 pad cols 612..639 = 0 (avoid NaN-poison from workspace)
        unsigned i = e - O10;
        int m = (int)(i / 28u), t = (int)(i % 28u);
        Z3[(size_t)m * 640 + 612 + t] = f2b(0.f);
    }
}

// ---------------- async global->LDS, 16B per lane (m97 idiom) --------------------
__device__ __forceinline__ void gload_lds16(const bf16* g, const bf16* lds_wave_base)
{
    unsigned off = (unsigned)(uintptr_t)lds_wave_base;
    off = __builtin_amdgcn_readfirstlane(off);
    __builtin_amdgcn_global_load_lds((const __attribute__((address_space(1))) unsigned int*)g,
                                     (__attribute__((address_space(3))) unsigned int*)off,
                                     16, 0, 0);
}

__device__ __forceinline__ int imin(int a, int b) { return a < b ? a : b; }
__device__ __forceinline__ int imax(int a, int b) { return a > b ? a : b; }

// ---------------- MFMA GEMM: rect K-banding + XCD swizzle ------------------------
// C[M,N] = A[M,K] @ B[N,K]^T. 1D grid = ntiles*mtiles, mtiles % 8 == 0.
// EPI: 0 bias+relu+sincos->C ; 1 bias+relu->C ;
//      2 bias+relu+sincos -> scatter into Z_next (window WN, corner offset 6-WN) ;
//      3 bias,*xc(from Afin)->out(fp32)
template<int EPI, int WS, int WN>
__global__ __launch_bounds__(256)
void gemm_bt(const bf16* __restrict__ A, const bf16* __restrict__ Bm, int KD,
             const float* __restrict__ bias, int ntiles,
             bf16* __restrict__ C, int ldc, int nlimit,
             int m0g, bf16* __restrict__ znext,
             const bf16* __restrict__ afin_xc, float* __restrict__ outp)
{
    __shared__ bf16 As[128 * 32];
    __shared__ bf16 Bs[128 * 32];
    const int tid = threadIdx.x;
    const int wave = tid >> 6, lane = tid & 63;
    const int l15 = lane & 15, lq = lane >> 4;
    const int wr = (wave >> 1) * 64, wc = (wave & 1) * 64;

    const int id = blockIdx.x;
    const int mt8 = (int)gridDim.x / (ntiles * 8);   // m-tiles per XCD
    const int xcd = id & 7, local = id >> 3;
    const int m_idx = xcd * mt8 + local / ntiles;
    const int n_idx = local % ntiles;
    const int n0 = n_idx * 128, m0 = m_idx * 128;

    int nspans = 1, sbeg[4], send[4];
    sbeg[0] = 0; send[0] = KD;
    if (WS > 0) {
        int po_lo = imin(n0 / 68, WS * WS - 1);
        int po_hi = imin((n0 + 127) / 68, WS * WS - 1);
        int ro_lo = po_lo / WS, ro_hi = po_hi / WS;
        int r_lo = imax(ro_lo - 1, 0), r_hi = imin(ro_hi + 1, WS - 1);
        int ci_lo = 0, ci_hi = WS - 1;
        if (ro_lo == ro_hi) {
            ci_lo = imax(po_lo % WS - 1, 0);
            ci_hi = imin(po_hi % WS + 1, WS - 1);
        }
        if (ci_lo == 0 && ci_hi == WS - 1) {
            sbeg[0] = (r_lo * WS * 68) & ~31;
            send[0] = imin(KD, ((r_hi + 1) * WS * 68 + 31) & ~31);
        } else {
            nspans = 0;
            for (int ri = r_lo; ri <= r_hi; ri++) {
                sbeg[nspans] = ((ri * WS + ci_lo) * 68) & ~31;
                send[nspans] = imin(KD, (((ri * WS + ci_hi + 1) * 68) + 31) & ~31);
                nspans++;
            }
        }
    }

    float bj[4];
    #pragma unroll
    for (int j = 0; j < 4; j++) bj[j] = bias[n0 + wc + j * 16 + l15];

    const bf16* Ab = A + (size_t)m0 * KD;
    const bf16* Bb = Bm + (size_t)n0 * KD;
    const int srow = tid >> 2, scol = (tid & 3) * 8;
    const bf16* aG0 = Ab + (size_t)srow * KD + scol;
    const bf16* aG1 = Ab + (size_t)(srow + 64) * KD + scol;
    const bf16* bG0 = Bb + (size_t)srow * KD + scol;
    const bf16* bG1 = Bb + (size_t)(srow + 64) * KD + scol;
    const bf16* lA0 = &As[wave * 512];
    const bf16* lA1 = &As[2048 + wave * 512];
    const bf16* lB0 = &Bs[wave * 512];
    const bf16* lB1 = &Bs[2048 + wave * 512];

    f32x4 acc[4][4];
    #pragma unroll
    for (int i = 0; i < 4; i++)
        #pragma unroll
        for (int j = 0; j < 4; j++) { f32x4 z = {0.f, 0.f, 0.f, 0.f}; acc[i][j] = z; }

    for (int s = 0; s < nspans; s++) {
        for (int k0 = sbeg[s]; k0 < send[s]; k0 += 32) {
            gload_lds16(aG0 + k0, lA0);
            gload_lds16(aG1 + k0, lA1);
            gload_lds16(bG0 + k0, lB0);
            gload_lds16(bG1 + k0, lB1);
            __syncthreads();
            short8 af[4], bg[4];
            #pragma unroll
            for (int i = 0; i < 4; i++) af[i] = *(const short8*)&As[(wr + i * 16 + l15) * 32 + lq * 8];
            #pragma unroll
            for (int j = 0; j < 4; j++) bg[j] = *(const short8*)&Bs[(wc + j * 16 + l15) * 32 + lq * 8];
            #pragma unroll
            for (int i = 0; i < 4; i++)
                #pragma unroll
                for (int j = 0; j < 4; j++)
                    acc[i][j] = __builtin_amdgcn_mfma_f32_16x16x32_bf16(af[i], bg[j], acc[i][j], 0, 0, 0);
            __syncthreads();
        }
    }

    #pragma unroll
    for (int i = 0; i < 4; i++) {
        #pragma unroll
        for (int j = 0; j < 4; j++) {
            int n = n0 + wc + j * 16 + l15;
            #pragma unroll
            for (int r = 0; r < 4; r++) {
                int m = m0 + wr + i * 16 + lq * 4 + r;
                float v = acc[i][j][r];
                if (EPI == 0) {
                    if (n < nlimit) {
                        v += bj[j]; v = fmaxf(v, 0.f); v = sincos_sum(v);
                        C[(size_t)m * ldc + n] = f2b(v);
                    }
                } else if (EPI == 1) {
                    if (n < nlimit) {
                        v += bj[j]; v = fmaxf(v, 0.f);
                        C[(size_t)m * ldc + n] = f2b(v);
                    }
                } else if (EPI == 2) {
                    if (n < 576) {
                        v += bj[j]; v = fmaxf(v, 0.f);
                        bf16 t = f2b(sincos_sum(v));
                        int gm = m0g + m;
                        int q = gm >> 13, b = gm & (BN - 1);
                        int ch = n / 9, p = n % 9;
                        int R = p / 3 + (q >> 1) * 3, Cc = p % 3 + (q & 1) * 3;
                        constexpr int OFF = 6 - WN;
                        constexpr int KDN = (WN == 4) ? 1088 : 640;
                        #pragma unroll
                        for (int qr = 0; qr < 2; qr++) {
                            int rr = R - OFF * qr;
                            if (rr < 0 || rr >= WN) continue;
                            #pragma unroll
                            for (int qc = 0; qc < 2; qc++) {
                                int cc = Cc - OFF * qc;
                                if (cc < 0 || cc >= WN) continue;
                                int pi = rr * WN + cc;
                                znext[((size_t)((qr * 2 + qc) * BN + b)) * KDN + pi * 68 + ch] = t;
                            }
                        }
                    }
                } else {
                    if (n < 64) {
                        v += bj[j];
                        int gm = m0g + m;
                        int f = gm * 64 + n;        // c-flat == out-flat
                        int b2 = f >> 8, rem = f & 255;
                        int ch2 = rem >> 2, ii = (rem >> 1) & 1, jj = rem & 1;
                        int qq = ii * 2 + jj;
                        const int offt[4] = {8, 6, 2, 0};
                        float xc = b2f(afin_xc[((size_t)qq * BN + b2) * 576 + ch2 * 9 + offt[qq]]);
                        outp[f] = v * xc;
                    }
                }
            }
        }
    }
}

extern "C" void kernel_launch(void* const* d_in, const int* in_sizes, int n_in,
                              void* d_out, int out_size, void* d_ws, size_t ws_size,
                              hipStream_t stream)
{
    const float* x    = (const float*)d_in[0];
    const float* cell = (const float*)d_in[1];
    const float* isc  = (const float*)d_in[2];
    const float* c1w  = (const float*)d_in[3];
    const float* c1b  = (const float*)d_in[4];
    const float* c3w  = (const float*)d_in[5];
    const float* c3b  = (const float*)d_in[6];
    const float* l5w  = (const float*)d_in[7];
    const float* l5b  = (const float*)d_in[8];
    const float* l4w  = (const float*)d_in[9];
    const float* l4b  = (const float*)d_in[10];
    const float* l3w  = (const float*)d_in[11];
    const float* l3b  = (const float*)d_in[12];
    const float* fw   = (const float*)d_in[13];
    const float* fb   = (const float*)d_in[14];

    char* base = (char*)d_ws;
    size_t cur = 0;
    auto take = [&](size_t bytes) -> char* {
        char* r = base + cur; cur += (bytes + 255) & ~(size_t)255; return r;
    };

    const size_t Z4B = (size_t)MTOT * 1088 * 2;   // 71.3 MB
    const size_t Z3B = (size_t)MTOT * 640 * 2;    // 41.9 MB
    const size_t AFB = (size_t)MTOT * 576 * 2;    // 37.7 MB
    size_t wbytes = 2 * (1792ull * 1728 + 1152ull * 1088 + 640ull * 640) * 2
                  + (640ull * 1728 + 640ull * 1088 + 640ull * 640) * 2
                  + 128ull * 576 * 2 + 9216ull * 4 + 64 * 256;
    auto need = [&](int nc) -> size_t {
        return Z4B + Z3B + AFB + wbytes + 2 * ((size_t)(MTOT / nc) * 1728 * 2);
    };
    int nchunk = (ws_size >= need(1)) ? 1 : (ws_size >= need(2)) ? 2
               : (ws_size >= need(4)) ? 4 : (ws_size >= need(8)) ? 8 : 16;

    bf16* Z4   = (bf16*)take(Z4B);
    bf16* Z3   = (bf16*)take(Z3B);
    bf16* afinb = (bf16*)take(AFB);
    bf16* w1d5 = (bf16*)take(1792ull * 1728 * 2);
    bf16* w3d5 = (bf16*)take(1792ull * 1728 * 2);
    bf16* w1d4 = (bf16*)take(1152ull * 1088 * 2);
    bf16* w3d4 = (bf16*)take(1152ull * 1088 * 2);
    bf16* w1d3 = (bf16*)take(640ull * 640 * 2);
    bf16* w3d3 = (bf16*)take(640ull * 640 * 2);
    bf16* wl5p = (bf16*)take(640ull * 1728 * 2);
    bf16* wl4p = (bf16*)take(640ull * 1088 * 2);
    bf16* wl3p = (bf16*)take(640ull * 640 * 2);
    bf16* wfp  = (bf16*)take(128ull * 576 * 2);
    float* biasb = (float*)take(9216ull * 4);
    int CM = MTOT / nchunk;
    int mt = CM / 128;                          // divisible by 8 for nchunk<=16
    bf16* Za = (bf16*)take((size_t)CM * 1728 * 2);
    bf16* Zb = (bf16*)take((size_t)CM * 1728 * 2);

    // -------- stage 0: all weight repacks, bias, Z4/Z3 const cols, Z3 pad --------
    {
        constexpr unsigned OT = 2u*1792*1728 + 2u*1152*1088 + 2u*640*640
                              + 640u*1728 + 640u*1088 + 640u*640 + 128u*576 + 9216
                              + 4u*8192*16*4 + 4u*8192*9*4 + 32768u*28;
        megabuild<<<(OT + 255) / 256, 256, 0, stream>>>(
            c1w, c3w, l5w, l4w, l3w, fw, c1b, c3b, l5b, l4b, l3b, fb, cell, isc,
            w1d5, w3d5, w1d4, w3d4, w1d3, w3d3, wl5p, wl4p, wl3p, wfp, biasb, Z4, Z3);
    }

    // -------- ws=5: zprep -> conv1 -> conv3 -> lin (scatter into Z4) -------------
    for (int c = 0; c < nchunk; c++) {
        int m0g = c * CM;
        zprep_block<<<BN, 256, 0, stream>>>(x, cell, isc, Za, m0g, CM);
        gemm_bt<0, 5, 0><<<14 * mt, 256, 0, stream>>>(Za, w1d5, 1728, biasb + 0, 14,
                                                      Zb, 1728, 1728, 0, nullptr, nullptr, nullptr);
        gemm_bt<1, 5, 0><<<14 * mt, 256, 0, stream>>>(Zb, w3d5, 1728, biasb + 1792, 14,
                                                      Za, 1728, 1728, 0, nullptr, nullptr, nullptr);
        gemm_bt<2, 0, 4><<<5 * mt, 256, 0, stream>>>(Za, wl5p, 1728, biasb + 7168, 5,
                                                     nullptr, 0, 0, m0g, Z4, nullptr, nullptr);
    }
    // -------- ws=4: conv1(Z4) -> conv3 -> lin (scatter into Z3) ------------------
    for (int c = 0; c < nchunk; c++) {
        int m0g = c * CM;
        gemm_bt<0, 4, 0><<<9 * mt, 256, 0, stream>>>(Z4 + (size_t)m0g * 1088, w1d4, 1088,
                                                     biasb + 3584, 9, Zb, 1088, 1088,
                                                     0, nullptr, nullptr, nullptr);
        gemm_bt<1, 4, 0><<<9 * mt, 256, 0, stream>>>(Zb, w3d4, 1088, biasb + 4736, 9,
                                                     Za, 1088, 1088, 0, nullptr, nullptr, nullptr);
        gemm_bt<2, 0, 3><<<5 * mt, 256, 0, stream>>>(Za, wl4p, 1088, biasb + 7808, 5,
                                                     nullptr, 0, 0, m0g, Z3, nullptr, nullptr);
    }
    // -------- ws=3: conv1(Z3) -> conv3 -> lin (-> afinb, identity layout) --------
    for (int c = 0; c < nchunk; c++) {
        int m0g = c * CM;
        gemm_bt<0, 3, 0><<<5 * mt, 256, 0, stream>>>(Z3 + (size_t)m0g * 640, w1d3, 640,
                                                     biasb + 5888, 5, Zb, 640, 640,
                                                     0, nullptr, nullptr, nullptr);
        gemm_bt<1, 3, 0><<<5 * mt, 256, 0, stream>>>(Zb, w3d3, 640, biasb + 6528, 5,
                                                     Za, 640, 640, 0, nullptr, nullptr, nullptr);
        gemm_bt<1, 0, 0><<<5 * mt, 256, 0, stream>>>(Za, wl3p, 640, biasb + 8448, 5,
                                                     afinb + (size_t)m0g * 576, 576, 576,
                                                     0, nullptr, nullptr, nullptr);
    }
    // -------- final: (afinb @ Wf) * xc --------------------------------------------
    for (int c = 0; c < nchunk; c++) {
        int m0g = c * CM;
        gemm_bt<3, 0, 0><<<mt, 256, 0, stream>>>(afinb + (size_t)m0g * 576, wfp, 576,
                                                 biasb + 9088, 1, nullptr, 0, 0, m0g,
                                                 nullptr, afinb, (float*)d_out);
    }
}